// Round 7
// baseline (458.039 us; speedup 1.0000x reference)
//
#include <hip/hip_runtime.h>
#include <hip/hip_bf16.h>
#include <stdint.h>

typedef __bf16 bf16;
typedef __attribute__((ext_vector_type(8))) __bf16 bf16x8;
typedef __attribute__((ext_vector_type(4))) __bf16 bf16x4;
typedef __attribute__((ext_vector_type(4))) float f32x4;

#define MFMA_BF16 __builtin_amdgcn_mfma_f32_16x16x32_bf16

static constexpr int NB = 4;      // batches
static constexpr int NN = 8192;   // sequence length
static constexpr int DM = 1024;   // d_model
static constexpr int DK = 128;    // d_k
static constexpr int NPART = 8;   // k_m partial-M buffers (atomic-free reduction)

#define GLDS16(gp, lp)                                                              \
  __builtin_amdgcn_global_load_lds((const __attribute__((address_space(1))) void*)(gp), \
                                   (__attribute__((address_space(3))) void*)(lp), 16, 0, 0)

// ---------------------------------------------------------------------------
// Kernel 0: build merged Wb[256][1024] bf16 (rows 0..127 = Wq, 128..255 = Wk).
// ---------------------------------------------------------------------------
__global__ __launch_bounds__(256) void k_prep(const float* __restrict__ Wq,
                                              const float* __restrict__ Wk,
                                              bf16* __restrict__ Wb) {
  const int i = blockIdx.x * 256 + threadIdx.x;  // 0..131071
  Wb[i] = (bf16)Wq[i];
  Wb[i + 131072] = (bf16)Wk[i];
}

// ---------------------------------------------------------------------------
// Kernel 1: Q = J @ Wq^T (row-major bf16), Kt = (J @ Wk^T)^T (k-major bf16)
// (frozen; < 80 us by fill-kernel bound)
// LDS: J 2x8KB [0,16K) ; W 2x16KB [16K,48K)
// ---------------------------------------------------------------------------
__global__ __launch_bounds__(256) void k_qk(const float* __restrict__ J,
                                            const bf16* __restrict__ Wb,
                                            bf16* __restrict__ Q,
                                            bf16* __restrict__ Kt) {
  __shared__ __align__(16) char lds[49152];
  const int t = threadIdx.x, w = t >> 6;
  const int l16 = t & 15, quad = (t >> 4) & 3;
  const int rbase = blockIdx.x * 64;

  f32x4 acc[16] = {};

  auto stage = [&](int c) {
    const int d0 = c * 32, buf = c & 1;
#pragma unroll
    for (int i = 0; i < 2; ++i) {
      int s = i * 256 + t;
      int r = s >> 3, sg = s & 7;
      int gc = sg ^ (r & 7);
      const float* gp = J + (size_t)(rbase + r) * DM + d0 + gc * 4;
      int off = __builtin_amdgcn_readfirstlane(buf * 8192 + (i * 256 + w * 64) * 16);
      GLDS16(gp, lds + off);
    }
#pragma unroll
    for (int i = 0; i < 4; ++i) {
      int s = i * 256 + t;
      int r = s >> 2, sg = s & 3;
      int gc = sg ^ ((r >> 1) & 3);
      const bf16* gp = Wb + (size_t)r * DM + d0 + gc * 8;
      int off = __builtin_amdgcn_readfirstlane(16384 + buf * 16384 + (i * 256 + w * 64) * 16);
      GLDS16(gp, lds + off);
    }
  };

  stage(0);
  for (int c = 0; c < 32; ++c) {
    __syncthreads();
    if (c < 31) stage(c + 1);
    const int buf = c & 1;
    const int r = w * 16 + l16;
    f32x4 ja = *(const f32x4*)(lds + buf * 8192 + ((r * 8 + ((2 * quad) ^ (r & 7))) * 16));
    f32x4 jb = *(const f32x4*)(lds + buf * 8192 + ((r * 8 + ((2 * quad + 1) ^ (r & 7))) * 16));
    bf16x8 a;
#pragma unroll
    for (int e = 0; e < 4; ++e) { a[e] = (bf16)ja[e]; a[4 + e] = (bf16)jb[e]; }
#pragma unroll
    for (int kt = 0; kt < 16; ++kt) {
      const int row = kt * 16 + l16;
      bf16x8 bfrag = *(const bf16x8*)(lds + 16384 + buf * 16384 +
                                      ((row * 4 + (quad ^ ((row >> 1) & 3))) * 16));
      acc[kt] = MFMA_BF16(a, bfrag, acc[kt], 0, 0, 0);
    }
  }

  const int row0 = rbase + w * 16 + quad * 4;
#pragma unroll
  for (int kt = 0; kt < 8; ++kt) {
    const int col = kt * 16 + l16;
#pragma unroll
    for (int r2 = 0; r2 < 4; ++r2)
      Q[(size_t)(row0 + r2) * DK + col] = (bf16)acc[kt][r2];
  }
  const int b = rbase >> 13;
  const int nloc = (rbase & (NN - 1)) + w * 16 + quad * 4;
#pragma unroll
  for (int kt = 0; kt < 8; ++kt) {
    const int k = kt * 16 + l16;
    bf16x4 pv;
#pragma unroll
    for (int r2 = 0; r2 < 4; ++r2) pv[r2] = (bf16)acc[8 + kt][r2];
    *(bf16x4*)(Kt + (size_t)(b * DK + k) * NN + nloc) = pv;
  }
}

// ---------------------------------------------------------------------------
// Kernel 2: Mt partials, atomic-free (frozen; < 80 us).
// LDS: J 2x16KB [0,32K) ; Kt 2x4KB [32K,40K)
// ---------------------------------------------------------------------------
__global__ __launch_bounds__(256) void k_m(const float* __restrict__ J,
                                           const bf16* __restrict__ Kt,
                                           float* __restrict__ Mt) {
  __shared__ __align__(16) char lds[40960];
  const int bid = blockIdx.x;
  const int kh = bid & 1, b = (bid >> 1) & 3, dch = (bid >> 3) & 7, ns = bid >> 6;
  const int t = threadIdx.x, w = t >> 6;
  const int l16 = t & 15, quad = (t >> 4) & 3;
  const float* Jb = J + (size_t)b * NN * DM + (size_t)(ns * 1024) * DM + dch * 128;
  const bf16* Ktb = Kt + (size_t)(b * DK) * NN + ns * 1024;

  f32x4 acc[2][4] = {};

  auto stage = [&](int c) {
    const int buf = c & 1, n0 = c * 32;
#pragma unroll
    for (int i = 0; i < 4; ++i) {
      int s = i * 256 + t;
      int n = s >> 5, sg = s & 31;
      int gc = sg ^ (2 * ((n >> 3) & 3));
      const float* gp = Jb + (size_t)(n0 + n) * DM + gc * 4;
      int off = __builtin_amdgcn_readfirstlane(buf * 16384 + (i * 256 + w * 64) * 16);
      GLDS16(gp, lds + off);
    }
    {
      int s = t;
      int k = s >> 2, sg = s & 3;
      int gc = sg ^ ((k >> 1) & 3);
      const bf16* gp = Ktb + (size_t)(kh * 64 + k) * NN + n0 + gc * 8;
      int off = __builtin_amdgcn_readfirstlane(32768 + buf * 4096 + (w * 64) * 16);
      GLDS16(gp, lds + off);
    }
  };

  stage(0);
  for (int c = 0; c < 32; ++c) {
    __syncthreads();
    if (c < 31) stage(c + 1);
    const int buf = c & 1;
    bf16x8 af[2];
#pragma unroll
    for (int dt = 0; dt < 2; ++dt) {
      const int gc = w * 8 + dt * 4 + (l16 >> 2);
      const int db = (l16 & 3) * 4;
#pragma unroll
      for (int p = 0; p < 4; ++p) {
        const int n = quad * 8 + 2 * p;
        const int slot = n * 32 + (gc ^ (2 * quad));
        const char* base = lds + buf * 16384 + slot * 16 + db;
        float f0 = *(const float*)base;
        float f1 = *(const float*)(base + 512);
        af[dt][2 * p] = (bf16)f0;
        af[dt][2 * p + 1] = (bf16)f1;
      }
    }
#pragma unroll
    for (int kt = 0; kt < 4; ++kt) {
      const int k = kt * 16 + l16;
      bf16x8 bfrag = *(const bf16x8*)(lds + 32768 + buf * 4096 +
                                      ((k * 4 + (quad ^ ((k >> 1) & 3))) * 16));
      acc[0][kt] = MFMA_BF16(af[0], bfrag, acc[0][kt], 0, 0, 0);
      acc[1][kt] = MFMA_BF16(af[1], bfrag, acc[1][kt], 0, 0, 0);
    }
  }

  float* Pp = Mt + (size_t)ns * (NB * DM * DK);
#pragma unroll
  for (int dt = 0; dt < 2; ++dt) {
    const int d = dch * 128 + w * 32 + dt * 16 + quad * 4;
#pragma unroll
    for (int kt = 0; kt < 4; ++kt) {
      const int k = kh * 64 + kt * 16 + l16;
#pragma unroll
      for (int r = 0; r < 4; ++r)
        Pp[(size_t)(b * DM + d + r) * DK + k] = acc[dt][kt][r];
    }
  }
}

// ---------------------------------------------------------------------------
// Kernel 2b: reduce 8 Mt partials, fold 1/sqrt(128), convert to bf16.
// ---------------------------------------------------------------------------
__global__ __launch_bounds__(256) void k_cvt(const float* __restrict__ Mt,
                                             bf16* __restrict__ Mtb) {
  const float s = 0.08838834764831845f;  // 1/sqrt(128)
  const int total = NB * DM * DK;        // 524288
  for (int i = blockIdx.x * 256 + threadIdx.x; i < total; i += 512 * 256) {
    float a = 0.f;
#pragma unroll
    for (int p = 0; p < NPART; ++p) a += Mt[(size_t)p * total + i];
    Mtb[i] = (bf16)(a * s);
  }
}

// ---------------------------------------------------------------------------
// Kernel 3 NEW: k_fol = fused (Q@M + J) -> LN -> out, k_qk-style LDS pipeline.
// Diagnosis r0-r5: five flat-load variants all ~110us (latency-serialized L2
// M-loads, 2 waves/SIMD, compiler refuses deep register MLP). The only
// pattern beating latency on this chip is the glds double-buffer (k_qk/k_m
// both < 80us with MORE traffic). Also 16-row blocks re-read all of M ->
// 512MB L2 traffic; 64-row blocks cut that 4x and share the LDS-staged chunk
// across 4 waves.
// Structure: 512 blocks x 64 rows. Q-frags hoisted to regs (r2 layout).
// Loop 8 d-chunks of 128: M chunk [128d][128k] bf16 = 32KB, double-buffered
// (LDS 64KB, 2 blocks/CU), granule XOR-swizzle (slot g = src_g ^ (d&7)).
// Per chunk/wave: 32 MFMA from LDS + J add (read once, HBM) + LN sums in
// regs + x spill to X scratch (bf16, L2-hot). Pass 2 in-kernel: fence +
// barrier, per-row stats via shfl, fully-coalesced f32x4 normalize+store.
// ---------------------------------------------------------------------------
__global__ __launch_bounds__(256, 2) void k_fol(const float* __restrict__ J,
                                                const bf16* __restrict__ Q,
                                                const bf16* __restrict__ Mtb,
                                                const float* __restrict__ gamma,
                                                const float* __restrict__ beta,
                                                bf16* __restrict__ X,
                                                float* __restrict__ out) {
  __shared__ __align__(16) char lds[65536];  // M double buffer 2x32KB
  const int t = threadIdx.x, w = t >> 6, lane = t & 63;
  const int l16 = t & 15, quad = (t >> 4) & 3;
  const int rbase = blockIdx.x * 64;
  const int b = rbase >> 13;
  const bf16* Mb = Mtb + (size_t)b * DM * DK;  // [d][k] row-major
  const int nrow = rbase + w * 16 + l16;       // this lane's output row

  // Q B-frags in registers (r2-verified): lane l16 -> row nrow, k = ks*32+quad*8
  bf16x8 bq[4];
#pragma unroll
  for (int ks = 0; ks < 4; ++ks)
    bq[ks] = *(const bf16x8*)(Q + (size_t)nrow * DK + ks * 32 + quad * 8);

  // stage M chunk c: LDS slot (d, g) <- global granule (d, g ^ (d&7))
  auto stageM = [&](int c) {
    const int buf = c & 1;
    const bf16* Mc = Mb + (size_t)(c * 128) * DK;
#pragma unroll
    for (int i = 0; i < 8; ++i) {
      int s = i * 256 + t, d = s >> 4, g = s & 15, gc = g ^ (d & 7);
      int off = __builtin_amdgcn_readfirstlane(buf * 32768 + (i * 256 + w * 64) * 16);
      GLDS16(Mc + (size_t)d * DK + gc * 8, lds + off);
    }
  };

  stageM(0);
  float s1 = 0.f, s2 = 0.f;

  for (int c = 0; c < 8; ++c) {
    __syncthreads();               // drains glds (vmcnt) + joins waves
    if (c < 7) stageM(c + 1);      // DMA next chunk under compute
    const int buf = c & 1;

    // J loads for this chunk (independent; issue early, land under MFMAs)
    f32x4 jreg[8];
#pragma unroll
    for (int dt = 0; dt < 8; ++dt)
      jreg[dt] = *(const f32x4*)(J + (size_t)nrow * DM + c * 128 + dt * 16 + quad * 4);

    // acc[dt]: (QM)[n=nrow][d = c*128 + dt*16 + quad*4 .. +3]
    f32x4 acc[8] = {};
#pragma unroll
    for (int ks = 0; ks < 4; ++ks) {
#pragma unroll
      for (int dt = 0; dt < 8; ++dt) {
        bf16x8 a = *(const bf16x8*)(lds + buf * 32768 +
            (((dt * 16 + l16) * 16 + ((ks * 4 + quad) ^ (l16 & 7))) * 16));
        acc[dt] = MFMA_BF16(a, bq[ks], acc[dt], 0, 0, 0);
      }
    }

    // x = QM + J; accumulate LN sums; spill x to scratch (bf16)
#pragma unroll
    for (int dt = 0; dt < 8; ++dt) {
      f32x4 v = acc[dt] + jreg[dt];
      s1 += v[0] + v[1] + v[2] + v[3];
      s2 += v[0] * v[0] + v[1] * v[1] + v[2] * v[2] + v[3] * v[3];
      bf16x4 xv;
#pragma unroll
      for (int r = 0; r < 4; ++r) xv[r] = (bf16)v[r];
      *(bf16x4*)(X + (size_t)nrow * DM + c * 128 + dt * 16 + quad * 4) = xv;
    }
  }

  // per-row stats (quads share a row: reduce across lane bits 4-5)
  s1 += __shfl_xor(s1, 16); s2 += __shfl_xor(s2, 16);
  s1 += __shfl_xor(s1, 32); s2 += __shfl_xor(s2, 32);
  const float mu0 = s1 * (1.0f / DM);
  const float inv0 = rsqrtf(s2 * (1.0f / DM) - mu0 * mu0 + 1e-5f);

  __threadfence();     // X stores visible through L2
  __syncthreads();

  // pass 2: coalesced normalize. Wave w owns rows w*16..+15 (it wrote them).
  f32x4 g4[4], b4[4];
#pragma unroll
  for (int i = 0; i < 4; ++i) {
    g4[i] = *(const f32x4*)(gamma + i * 256 + lane * 4);
    b4[i] = *(const f32x4*)(beta + i * 256 + lane * 4);
  }
  for (int r2 = 0; r2 < 16; ++r2) {
    const int n2 = rbase + w * 16 + r2;
    const float mur = __shfl(mu0, r2);   // lane l16==r2 holds row r2's stats
    const float invr = __shfl(inv0, r2);
#pragma unroll
    for (int i = 0; i < 4; ++i) {
      const int d = i * 256 + lane * 4;
      bf16x4 xv = *(const bf16x4*)(X + (size_t)n2 * DM + d);
      f32x4 v;
#pragma unroll
      for (int e = 0; e < 4; ++e) v[e] = (float)xv[e];
      f32x4 o = (v - mur) * invr * g4[i] + b4[i];
      *(f32x4*)(out + (size_t)n2 * DM + d) = o;
    }
  }
}

// ---------------------------------------------------------------------------
// Kernel 3 fallback (r2): fused flat-load version, used only if workspace
// lacks room for the X scratch.
// ---------------------------------------------------------------------------
__global__ __launch_bounds__(256, 4) void k_out(const float* __restrict__ J,
                                                const bf16* __restrict__ Q,
                                                const bf16* __restrict__ Mtb,
                                                const float* __restrict__ gamma,
                                                const float* __restrict__ beta,
                                                float* __restrict__ out) {
  __shared__ float S[4][16][2];
  const int t = threadIdx.x, w = t >> 6;
  const int l16 = t & 15, quad = (t >> 4) & 3;
  const int nbase = blockIdx.x * 16;
  const int b = nbase >> 13;
  const int dbase = w * 256;
  const bf16* M = Mtb + (size_t)b * DM * DK;

  bf16x8 bq[4];
#pragma unroll
  for (int i = 0; i < 4; ++i)
    bq[i] = *(const bf16x8*)(Q + (size_t)(nbase + l16) * DK + i * 32 + quad * 8);

  f32x4 acc[16] = {};
#pragma unroll
  for (int ks = 0; ks < 4; ++ks) {
#pragma unroll
    for (int ct = 0; ct < 16; ++ct) {
      bf16x8 am = *(const bf16x8*)(M + (size_t)(dbase + ct * 16 + l16) * DK +
                                   ks * 32 + quad * 8);
      acc[ct] = MFMA_BF16(am, bq[ks], acc[ct], 0, 0, 0);
    }
  }

  const int n = nbase + l16;
  float s1 = 0.f, s2 = 0.f;
#pragma unroll
  for (int ct = 0; ct < 16; ++ct) {
    f32x4 jv = *(const f32x4*)(J + (size_t)n * DM + dbase + ct * 16 + quad * 4);
    f32x4 v = acc[ct] + jv;
    acc[ct] = v;
    s1 += v[0] + v[1] + v[2] + v[3];
    s2 += v[0] * v[0] + v[1] * v[1] + v[2] * v[2] + v[3] * v[3];
  }
  s1 += __shfl_xor(s1, 16); s2 += __shfl_xor(s2, 16);
  s1 += __shfl_xor(s1, 32); s2 += __shfl_xor(s2, 32);
  if (quad == 0) { S[w][l16][0] = s1; S[w][l16][1] = s2; }
  __syncthreads();
  const float a1 = S[0][l16][0] + S[1][l16][0] + S[2][l16][0] + S[3][l16][0];
  const float a2 = S[0][l16][1] + S[1][l16][1] + S[2][l16][1] + S[3][l16][1];
  const float mu = a1 * (1.0f / DM);
  const float inv = rsqrtf(a2 * (1.0f / DM) - mu * mu + 1e-5f);

#pragma unroll
  for (int ct = 0; ct < 16; ++ct) {
    const int d = dbase + ct * 16 + quad * 4;
    f32x4 g = *(const f32x4*)(gamma + d);
    f32x4 be = *(const f32x4*)(beta + d);
    f32x4 o = (acc[ct] - mu) * inv * g + be;
    *(f32x4*)(out + (size_t)n * DM + d) = o;
  }
}

// ---------------------------------------------------------------------------
// launch
// ---------------------------------------------------------------------------
extern "C" void kernel_launch(void* const* d_in, const int* in_sizes, int n_in,
                              void* d_out, int out_size, void* d_ws, size_t ws_size,
                              hipStream_t stream) {
  const float* J = (const float*)d_in[0];
  const float* Wq = (const float*)d_in[1];
  const float* Wk = (const float*)d_in[2];
  const float* gamma = (const float*)d_in[3];
  const float* beta = (const float*)d_in[4];
  float* out = (float*)d_out;

  // workspace: Mt_p fp32 8x2MB [0,16M); Mt_b bf16 [16M,17M); Q bf16 [17M,25M);
  //            Kt bf16 [25M,33M); Wb bf16 [33M,33.5M); X bf16 [34M,98M)
  char* ws = (char*)d_ws;
  float* Mt_f = (float*)ws;
  bf16* Mt_b = (bf16*)(ws + ((size_t)16 << 20));
  bf16* Qw = (bf16*)(ws + ((size_t)17 << 20));
  bf16* Ktw = (bf16*)(ws + ((size_t)25 << 20));
  bf16* Wb = (bf16*)(ws + ((size_t)33 << 20));
  bf16* Xw = (bf16*)(ws + ((size_t)34 << 20));

  k_prep<<<512, 256, 0, stream>>>(Wq, Wk, Wb);
  k_qk<<<512, 256, 0, stream>>>(J, Wb, Qw, Ktw);
  k_m<<<512, 256, 0, stream>>>(J, Ktw, Mt_f);
  k_cvt<<<512, 256, 0, stream>>>(Mt_f, Mt_b);

  if (ws_size >= ((size_t)98 << 20)) {
    k_fol<<<512, 256, 0, stream>>>(J, Qw, Mt_b, gamma, beta, Xw, out);
  } else {
    k_out<<<2048, 256, 0, stream>>>(J, Qw, Mt_b, gamma, beta, out);
  }
}

// Round 8
// 369.314 us; speedup vs baseline: 1.2402x; 1.2402x over previous
//
#include <hip/hip_runtime.h>
#include <hip/hip_bf16.h>
#include <stdint.h>

typedef __bf16 bf16;
typedef __attribute__((ext_vector_type(8))) __bf16 bf16x8;
typedef __attribute__((ext_vector_type(4))) __bf16 bf16x4;
typedef __attribute__((ext_vector_type(4))) float f32x4;

#define MFMA_BF16 __builtin_amdgcn_mfma_f32_16x16x32_bf16

static constexpr int NB = 4;      // batches
static constexpr int NN = 8192;   // sequence length
static constexpr int DM = 1024;   // d_model
static constexpr int DK = 128;    // d_k
static constexpr int NPART = 16;  // k_m partial-M buffers (atomic-free reduction)

#define GLDS16(gp, lp)                                                              \
  __builtin_amdgcn_global_load_lds((const __attribute__((address_space(1))) void*)(gp), \
                                   (__attribute__((address_space(3))) void*)(lp), 16, 0, 0)

// ---------------------------------------------------------------------------
// Kernel 0: build merged Wb[256][1024] bf16 (rows 0..127 = Wq, 128..255 = Wk).
// ---------------------------------------------------------------------------
__global__ __launch_bounds__(256) void k_prep(const float* __restrict__ Wq,
                                              const float* __restrict__ Wk,
                                              bf16* __restrict__ Wb) {
  const int i = blockIdx.x * 256 + threadIdx.x;  // 0..131071
  Wb[i] = (bf16)Wq[i];
  Wb[i + 131072] = (bf16)Wk[i];
}

// ---------------------------------------------------------------------------
// Kernel 1: Q = J @ Wq^T (row-major bf16), Kt = (J @ Wk^T)^T (k-major bf16)
// r0 version (J read exactly once). glds-staged, double-buffered, swizzled.
// LDS: J 2x8KB [0,16K) ; W 2x16KB [16K,48K)
// ---------------------------------------------------------------------------
__global__ __launch_bounds__(256) void k_qk(const float* __restrict__ J,
                                            const bf16* __restrict__ Wb,
                                            bf16* __restrict__ Q,
                                            bf16* __restrict__ Kt) {
  __shared__ __align__(16) char lds[49152];
  const int t = threadIdx.x, w = t >> 6;
  const int l16 = t & 15, quad = (t >> 4) & 3;
  const int rbase = blockIdx.x * 64;

  f32x4 acc[16] = {};

  auto stage = [&](int c) {
    const int d0 = c * 32, buf = c & 1;
#pragma unroll
    for (int i = 0; i < 2; ++i) {
      int s = i * 256 + t;
      int r = s >> 3, sg = s & 7;
      int gc = sg ^ (r & 7);
      const float* gp = J + (size_t)(rbase + r) * DM + d0 + gc * 4;
      int off = __builtin_amdgcn_readfirstlane(buf * 8192 + (i * 256 + w * 64) * 16);
      GLDS16(gp, lds + off);
    }
#pragma unroll
    for (int i = 0; i < 4; ++i) {
      int s = i * 256 + t;
      int r = s >> 2, sg = s & 3;
      int gc = sg ^ ((r >> 1) & 3);
      const bf16* gp = Wb + (size_t)r * DM + d0 + gc * 8;
      int off = __builtin_amdgcn_readfirstlane(16384 + buf * 16384 + (i * 256 + w * 64) * 16);
      GLDS16(gp, lds + off);
    }
  };

  stage(0);
  for (int c = 0; c < 32; ++c) {
    __syncthreads();              // drains own-wave glds (vmcnt) + joins waves
    if (c < 31) stage(c + 1);     // DMA of next chunk overlaps compute below
    const int buf = c & 1;
    const int r = w * 16 + l16;
    f32x4 ja = *(const f32x4*)(lds + buf * 8192 + ((r * 8 + ((2 * quad) ^ (r & 7))) * 16));
    f32x4 jb = *(const f32x4*)(lds + buf * 8192 + ((r * 8 + ((2 * quad + 1) ^ (r & 7))) * 16));
    bf16x8 a;
#pragma unroll
    for (int e = 0; e < 4; ++e) { a[e] = (bf16)ja[e]; a[4 + e] = (bf16)jb[e]; }
#pragma unroll
    for (int kt = 0; kt < 16; ++kt) {
      const int row = kt * 16 + l16;
      bf16x8 bfrag = *(const bf16x8*)(lds + 16384 + buf * 16384 +
                                      ((row * 4 + (quad ^ ((row >> 1) & 3))) * 16));
      acc[kt] = MFMA_BF16(a, bfrag, acc[kt], 0, 0, 0);
    }
  }

  // epilogue: Q row-major; Kt k-major (transposed via C-layout)
  const int row0 = rbase + w * 16 + quad * 4;
#pragma unroll
  for (int kt = 0; kt < 8; ++kt) {
    const int col = kt * 16 + l16;
#pragma unroll
    for (int r2 = 0; r2 < 4; ++r2)
      Q[(size_t)(row0 + r2) * DK + col] = (bf16)acc[kt][r2];
  }
  const int b = rbase >> 13;
  const int nloc = (rbase & (NN - 1)) + w * 16 + quad * 4;
#pragma unroll
  for (int kt = 0; kt < 8; ++kt) {
    const int k = kt * 16 + l16;
    bf16x4 pv;
#pragma unroll
    for (int r2 = 0; r2 < 4; ++r2) pv[r2] = (bf16)acc[8 + kt][r2];
    *(bf16x4*)(Kt + (size_t)(b * DK + k) * NN + nloc) = pv;
  }
}

// ---------------------------------------------------------------------------
// Kernel 2: Mt partials, r0 GEOMETRY (J read ONCE — the kh split since r1 was
// silently doubling J traffic to 256MB) + atomic-free stores (r3-proven).
// grid 512 = 4b x 8dch x 16ns; per block: 512-row n-range, 16 chunks of 32 n,
// full 128 k, output 128d x 128k partial -> Mt_p[ns].
// LDS: J 2x16KB [0,32K) ; Kt 2x8KB [32K,48K)
// ---------------------------------------------------------------------------
__global__ __launch_bounds__(256) void k_m(const float* __restrict__ J,
                                           const bf16* __restrict__ Kt,
                                           float* __restrict__ Mt) {
  __shared__ __align__(16) char lds[49152];
  const int bid = blockIdx.x;
  const int b = bid & 3, dch = (bid >> 2) & 7, ns = bid >> 5;
  const int t = threadIdx.x, w = t >> 6;
  const int l16 = t & 15, quad = (t >> 4) & 3;
  const float* Jb = J + (size_t)b * NN * DM + (size_t)(ns * 512) * DM + dch * 128;
  const bf16* Ktb = Kt + (size_t)(b * DK) * NN + ns * 512;

  f32x4 acc[2][8] = {};

  auto stage = [&](int c) {
    const int buf = c & 1, n0 = c * 32;
    // J tile: 32 n x 32 granules (granule = 4 fp32), swizzle sg = gc ^ (2*((n>>3)&3))
#pragma unroll
    for (int i = 0; i < 4; ++i) {
      int s = i * 256 + t;
      int n = s >> 5, sg = s & 31;
      int gc = sg ^ (2 * ((n >> 3) & 3));
      const float* gp = Jb + (size_t)(n0 + n) * DM + gc * 4;
      int off = __builtin_amdgcn_readfirstlane(buf * 16384 + (i * 256 + w * 64) * 16);
      GLDS16(gp, lds + off);
    }
    // Kt tile: 128 k x 4 granules (granule = 8 bf16), swizzle sg = gc ^ ((k>>1)&3)
#pragma unroll
    for (int i = 0; i < 2; ++i) {
      int s = i * 256 + t;
      int k = s >> 2, sg = s & 3;
      int gc = sg ^ ((k >> 1) & 3);
      const bf16* gp = Ktb + (size_t)k * NN + n0 + gc * 8;
      int off = __builtin_amdgcn_readfirstlane(32768 + buf * 8192 + (i * 256 + w * 64) * 16);
      GLDS16(gp, lds + off);
    }
  };

  stage(0);
  for (int c = 0; c < 16; ++c) {
    __syncthreads();
    if (c < 15) stage(c + 1);
    const int buf = c & 1;
    // A-frags: af[dt][j] = (bf16)J[n=quad*8+j][d = w*32 + dt*16 + l16]
    bf16x8 af[2];
#pragma unroll
    for (int dt = 0; dt < 2; ++dt) {
      const int gc = w * 8 + dt * 4 + (l16 >> 2);   // fp32 granule col of d
      const int db = (l16 & 3) * 4;                 // dword offset inside granule
#pragma unroll
      for (int p = 0; p < 4; ++p) {
        const int n = quad * 8 + 2 * p;
        const int slot = n * 32 + (gc ^ (2 * quad));
        const char* base = lds + buf * 16384 + slot * 16 + db;
        float f0 = *(const float*)base;          // J[n][d]
        float f1 = *(const float*)(base + 512);  // J[n+1][d] (next row, same swizzle)
        af[dt][2 * p] = (bf16)f0;
        af[dt][2 * p + 1] = (bf16)f1;
      }
    }
#pragma unroll
    for (int kt = 0; kt < 8; ++kt) {
      const int k = kt * 16 + l16;
      bf16x8 bfrag = *(const bf16x8*)(lds + 32768 + buf * 8192 +
                                      ((k * 4 + (quad ^ ((k >> 1) & 3))) * 16));
      acc[0][kt] = MFMA_BF16(af[0], bfrag, acc[0][kt], 0, 0, 0);
      acc[1][kt] = MFMA_BF16(af[1], bfrag, acc[1][kt], 0, 0, 0);
    }
  }

  // plain stores to the private partial (disjoint per block, full coverage)
  float* Pp = Mt + (size_t)ns * (NB * DM * DK);
#pragma unroll
  for (int dt = 0; dt < 2; ++dt) {
    const int d = dch * 128 + w * 32 + dt * 16 + quad * 4;
#pragma unroll
    for (int kt = 0; kt < 8; ++kt) {
      const int k = kt * 16 + l16;
#pragma unroll
      for (int r = 0; r < 4; ++r)
        Pp[(size_t)(b * DM + d + r) * DK + k] = acc[dt][kt][r];
    }
  }
}

// ---------------------------------------------------------------------------
// Kernel 2b: reduce 16 Mt partials, fold 1/sqrt(128), convert to bf16.
// ---------------------------------------------------------------------------
__global__ __launch_bounds__(256) void k_cvt(const float* __restrict__ Mt,
                                             bf16* __restrict__ Mtb) {
  const float s = 0.08838834764831845f;  // 1/sqrt(128)
  const int total = NB * DM * DK;        // 524288
  for (int i = blockIdx.x * 256 + threadIdx.x; i < total; i += 512 * 256) {
    float a = 0.f;
#pragma unroll
    for (int p = 0; p < NPART; ++p) a += Mt[(size_t)p * total + i];
    Mtb[i] = (bf16)(a * s);
  }
}

// ---------------------------------------------------------------------------
// Kernel 3: out = LN(Q @ M + J) * gamma + beta  (1/sqrt(dk) folded in Mtb)
// RESTORED r0 VERSION — measured 98 us, the best of six output-stage variants
// (coalesced 107-110, LDS-transpose 112, deep-ILP 110, glds k_fol 182).
// 16 rows/block, 2048 blocks; each wave 16 rows x 256 cols (acc = 64 VGPR).
// ---------------------------------------------------------------------------
__global__ __launch_bounds__(256) void k_out(const float* __restrict__ J,
                                             const bf16* __restrict__ Q,
                                             const bf16* __restrict__ Mtb,
                                             const float* __restrict__ gamma,
                                             const float* __restrict__ beta,
                                             float* __restrict__ out) {
  __shared__ float S[4][16][2];
  const int t = threadIdx.x, w = t >> 6;
  const int l16 = t & 15, quad = (t >> 4) & 3;
  const int rbase = blockIdx.x * 16;
  const int b = rbase >> 13;
  const int cbase = w * 256;
  const bf16* M = Mtb + (size_t)b * DM * DK;

  f32x4 acc[16] = {};
#pragma unroll
  for (int ks = 0; ks < DK; ks += 32) {
    bf16x8 aq = *(const bf16x8*)(Q + (size_t)(rbase + l16) * DK + ks + quad * 8);
#pragma unroll
    for (int ct = 0; ct < 16; ++ct) {
      bf16x8 bm = *(const bf16x8*)(M + (size_t)(cbase + ct * 16 + l16) * DK + ks + quad * 8);
      acc[ct] = MFMA_BF16(aq, bm, acc[ct], 0, 0, 0);
    }
  }

  float s1[4] = {}, s2[4] = {};
  const int row = rbase + quad * 4;
#pragma unroll
  for (int ct = 0; ct < 16; ++ct) {
    const int col = cbase + ct * 16 + l16;
    const float* jp = J + (size_t)row * DM + col;
#pragma unroll
    for (int r = 0; r < 4; ++r) {
      float x = acc[ct][r] + jp[(size_t)r * DM];
      acc[ct][r] = x;
      s1[r] += x;
      s2[r] += x * x;
    }
  }
#pragma unroll
  for (int off = 1; off < 16; off <<= 1)
#pragma unroll
    for (int r = 0; r < 4; ++r) {
      s1[r] += __shfl_xor(s1[r], off);
      s2[r] += __shfl_xor(s2[r], off);
    }
  if (l16 == 0)
#pragma unroll
    for (int r = 0; r < 4; ++r) {
      S[w][quad * 4 + r][0] = s1[r];
      S[w][quad * 4 + r][1] = s2[r];
    }
  __syncthreads();

  float mu[4], inv[4];
#pragma unroll
  for (int r = 0; r < 4; ++r) {
    const int lr = quad * 4 + r;
    float a1 = S[0][lr][0] + S[1][lr][0] + S[2][lr][0] + S[3][lr][0];
    float a2 = S[0][lr][1] + S[1][lr][1] + S[2][lr][1] + S[3][lr][1];
    float m = a1 * (1.0f / DM);
    float v = a2 * (1.0f / DM) - m * m;
    mu[r] = m;
    inv[r] = rsqrtf(v + 1e-5f);
  }
#pragma unroll
  for (int ct = 0; ct < 16; ++ct) {
    const int col = cbase + ct * 16 + l16;
    const float g = gamma[col], be = beta[col];
#pragma unroll
    for (int r = 0; r < 4; ++r)
      out[(size_t)(row + r) * DM + col] = (acc[ct][r] - mu[r]) * inv[r] * g + be;
  }
}

// ---------------------------------------------------------------------------
// launch
// ---------------------------------------------------------------------------
extern "C" void kernel_launch(void* const* d_in, const int* in_sizes, int n_in,
                              void* d_out, int out_size, void* d_ws, size_t ws_size,
                              hipStream_t stream) {
  const float* J = (const float*)d_in[0];
  const float* Wq = (const float*)d_in[1];
  const float* Wk = (const float*)d_in[2];
  const float* gamma = (const float*)d_in[3];
  const float* beta = (const float*)d_in[4];
  float* out = (float*)d_out;

  // workspace: Mt_p fp32 16x2MB [0,32M); Mt_b bf16 [32M,33M); Q bf16 [33M,41M);
  //            Kt bf16 [41M,49M); Wb bf16 [49M,49.5M)   (total 49.5 MiB)
  char* ws = (char*)d_ws;
  float* Mt_f = (float*)ws;
  bf16* Mt_b = (bf16*)(ws + ((size_t)32 << 20));
  bf16* Qw = (bf16*)(ws + ((size_t)33 << 20));
  bf16* Ktw = (bf16*)(ws + ((size_t)41 << 20));
  bf16* Wb = (bf16*)(ws + ((size_t)49 << 20));

  k_prep<<<512, 256, 0, stream>>>(Wq, Wk, Wb);
  k_qk<<<512, 256, 0, stream>>>(J, Wb, Qw, Ktw);
  k_m<<<512, 256, 0, stream>>>(J, Ktw, Mt_f);
  k_cvt<<<512, 256, 0, stream>>>(Mt_f, Mt_b);
  k_out<<<2048, 256, 0, stream>>>(J, Qw, Mt_b, gamma, beta, out);
}